// Round 7
// baseline (257.192 us; speedup 1.0000x reference)
//
#include <hip/hip_runtime.h>
#include <math.h>

// Problem constants (match reference)
#define B 32
#define C 4
#define P (360*640)        // 230400 pixels per batch
#define L 5                // MAX_LANES
#define DELTA_V 1.0f
#define DELTA_D 6.0f

#define BLKX 45            // chunks per batch; 225 wave-steps / 45 = 5 iters exactly
#define ITER1 5
#define NBLK3 (B*BLKX)     // 1440 pull partials
#define PSTRIDE 48         // padded chunk-stride of value-major partials

__device__ __forceinline__ float waveReduce(float v) {
#pragma unroll
    for (int off = 32; off; off >>= 1) v += __shfl_down(v, off, 64);
    return v;
}

// ---------------------------------------------------------------------------
// Kernel 1: segment sums, 2-channel split. Block = (chunk x, cpair, batch b).
// 3 streams (t + 2 channel planes), depth-2 flat SSA pipeline -> 6 x 16B loads
// in flight. t is read 2x (vs 4x in the R6 4-way split): 176 MB total.
// Partials are written VALUE-MAJOR: partial[(b*25+v)*48 + x], v = c*5+l for
// sums, 20+l for counts -- so K2 can reduce a batch's partials wave-parallel.
// ---------------------------------------------------------------------------
__global__ __launch_bounds__(256, 4) void seg_sums_k(const int* __restrict__ tgt,
                                                     const float* __restrict__ emb,
                                                     float* __restrict__ partial) {
    const int xb = blockIdx.x, cp = blockIdx.y, b = blockIdx.z;
    const int tid = threadIdx.x;
    const int c0 = 2 * cp;           // channels c0, c0+1

    const int4*   t4  = (const int4*)(tgt + (size_t)b * P);
    const float4* ea  = (const float4*)(emb + ((size_t)b * C + c0    ) * P);
    const float4* eb  = (const float4*)(emb + ((size_t)b * C + c0 + 1) * P);

    float s0[L], s1[L], n[L];
#pragma unroll
    for (int l = 0; l < L; ++l) { s0[l] = 0.f; s1[l] = 0.f; n[l] = 0.f; }

    auto acc1 = [&](int tt, float x0, float x1) {
#pragma unroll
        for (int l = 0; l < L; ++l) {
            float m = (tt == l + 1) ? 1.0f : 0.0f;
            n[l]  += m;
            s0[l]  = fmaf(m, x0, s0[l]);
            s1[l]  = fmaf(m, x1, s1[l]);
        }
    };
    auto consume = [&](const int4& tv, const float4& va, const float4& vb) {
        acc1(tv.x, va.x, vb.x);
        acc1(tv.y, va.y, vb.y);
        acc1(tv.z, va.z, vb.z);
        acc1(tv.w, va.w, vb.w);
    };

    // depth-2 flat software pipeline (SSA renames only -- no structs; R5's
    // struct pipeline spilled 195 MB to scratch)
    int g = xb * 256 + tid;
    int4   ta = t4[g];
    float4 pa = ea[g], pb = eb[g];
#pragma unroll
    for (int it = 0; it < ITER1 - 1; ++it) {
        const int gn = (xb + (it + 1) * BLKX) * 256 + tid;
        int4   tb = t4[gn];
        float4 qa = ea[gn], qb = eb[gn];
        consume(ta, pa, pb);
        ta = tb; pa = qa; pb = qb;
    }
    consume(ta, pa, pb);

    // block-reduce 15 values (10 sums + 5 counts; counts kept only from cp==0)
    float vals[15];
#pragma unroll
    for (int l = 0; l < L; ++l) { vals[l] = s0[l]; vals[L + l] = s1[l]; vals[10 + l] = n[l]; }

    __shared__ float red[4][15];
    const int lane = tid & 63, wave = tid >> 6;
#pragma unroll
    for (int k = 0; k < 15; ++k) {
        float r = waveReduce(vals[k]);
        if (lane == 0) red[wave][k] = r;
    }
    __syncthreads();
    if (tid < 15) {
        const float r = red[0][tid] + red[1][tid] + red[2][tid] + red[3][tid];
        int v;
        if (cp == 0) v = (tid < 10) ? tid : (tid + 10);      // c0,c1 sums; counts->20..24
        else         v = (tid < 10) ? (10 + tid) : -1;        // c2,c3 sums; drop dup counts
        if (v >= 0)
            partial[((size_t)b * 25 + v) * PSTRIDE + xb] = r;
    }
}

// ---------------------------------------------------------------------------
// Kernel 2: pull loss. Prologue derives this batch's means from the 4.5 KB of
// value-major partials (wave-parallel, ~1 us); x==0 blocks publish
// means/valid/cnt for kernel 3. Main loop: 5-stream depth-2 flat pipeline.
// ---------------------------------------------------------------------------
__global__ __launch_bounds__(256, 4) void pull_k(const int* __restrict__ tgt,
                                                 const float* __restrict__ emb,
                                                 const float* __restrict__ partial,
                                                 float* __restrict__ meansG,
                                                 float* __restrict__ validG,
                                                 float* __restrict__ cntvG,
                                                 float* __restrict__ pullp) {
    __shared__ float  praw[25];
    __shared__ float4 lmean[L + 1];   // label 0 -> zero mean
    __shared__ float  lvalid[L + 1];  // label 0 -> invalid
    __shared__ float  lred[4];
    const int xb = blockIdx.x, b = blockIdx.y;
    const int tid = threadIdx.x;
    const int lane = tid & 63, wave = tid >> 6;

    // ---- prologue: reduce partials (value-major) for batch b ----
    for (int v = wave; v < 25; v += 4) {
        float pv = (lane < BLKX) ? partial[((size_t)b * 25 + v) * PSTRIDE + lane] : 0.f;
        pv = waveReduce(pv);
        if (lane == 0) praw[v] = pv;
    }
    __syncthreads();
    if (tid < L) {
        const float cnt = praw[20 + tid];
        const bool  vld = cnt > 1.5f;          // integer count > 1
        const float inv = 1.0f / fmaxf(cnt, 1.0f);
        float4 m = make_float4(praw[tid] * inv, praw[5 + tid] * inv,
                               praw[10 + tid] * inv, praw[15 + tid] * inv);
        lmean[tid + 1]  = m;
        lvalid[tid + 1] = vld ? 1.f : 0.f;
        if (xb == 0) {                          // publish for finish_k
            *(float4*)(meansG + ((size_t)b * L + tid) * 4) = m;
            validG[b * L + tid] = vld ? 1.f : 0.f;
            cntvG[b * L + tid]  = vld ? cnt : 0.f;
        }
    }
    if (tid == 8) { lmean[0] = make_float4(0.f, 0.f, 0.f, 0.f); lvalid[0] = 0.f; }
    __syncthreads();

    // ---- main: 5-stream depth-2 flat pipeline ----
    const int4*   t4 = (const int4*)(tgt + (size_t)b * P);
    const float4* e0 = (const float4*)(emb + ((size_t)b * C + 0) * P);
    const float4* e1 = (const float4*)(emb + ((size_t)b * C + 1) * P);
    const float4* e2 = (const float4*)(emb + ((size_t)b * C + 2) * P);
    const float4* e3 = (const float4*)(emb + ((size_t)b * C + 3) * P);

    float acc = 0.f;
    auto proc1 = [&](int tt, float v0, float v1, float v2, float v3) {
        float4 m = lmean[tt];
        float d0 = v0 - m.x, d1 = v1 - m.y, d2 = v2 - m.z, d3 = v3 - m.w;
        float sq   = d0*d0 + d1*d1 + d2*d2 + d3*d3;
        float dist = sqrtf(fmaxf(sq, 1e-12f));
        float h    = fmaxf(dist - DELTA_V, 0.f);
        acc = fmaf(lvalid[tt] * h, h, acc);
    };

    int g = xb * 256 + tid;
    int4   ta = t4[g];
    float4 p0 = e0[g], p1 = e1[g], p2 = e2[g], p3 = e3[g];
#pragma unroll
    for (int it = 0; it < ITER1 - 1; ++it) {
        const int gn = (xb + (it + 1) * BLKX) * 256 + tid;
        int4   tb = t4[gn];
        float4 q0 = e0[gn], q1 = e1[gn], q2 = e2[gn], q3 = e3[gn];
        proc1(ta.x, p0.x, p1.x, p2.x, p3.x);
        proc1(ta.y, p0.y, p1.y, p2.y, p3.y);
        proc1(ta.z, p0.z, p1.z, p2.z, p3.z);
        proc1(ta.w, p0.w, p1.w, p2.w, p3.w);
        ta = tb; p0 = q0; p1 = q1; p2 = q2; p3 = q3;
    }
    proc1(ta.x, p0.x, p1.x, p2.x, p3.x);
    proc1(ta.y, p0.y, p1.y, p2.y, p3.y);
    proc1(ta.z, p0.z, p1.z, p2.z, p3.z);
    proc1(ta.w, p0.w, p1.w, p2.w, p3.w);

    float r = waveReduce(acc);
    if (lane == 0) lred[wave] = r;
    __syncthreads();
    if (tid == 0)
        pullp[b * BLKX + xb] = lred[0] + lred[1] + lred[2] + lred[3];
}

// ---------------------------------------------------------------------------
// Kernel 3: final combine — push loss + point_count + pull partial sum
// ---------------------------------------------------------------------------
__global__ __launch_bounds__(256) void finish_k(const float* __restrict__ pullp,
                                                const float* __restrict__ meansG,
                                                const float* __restrict__ validG,
                                                const float* __restrict__ cntvG,
                                                float* __restrict__ out) {
    __shared__ float red[4][4];
    const int tid = threadIdx.x;
    const int lane = tid & 63, wave = tid >> 6;

    float vb = 0.f, has = 0.f;
    if (tid < B) {
        const float* mb = meansG + tid * L * 4;
        const float* vv = validG + tid * L;
        float ssum = 0.f, np = 0.f;
#pragma unroll
        for (int i = 0; i < L; ++i)
#pragma unroll
            for (int j = i + 1; j < L; ++j) {
                float ok = vv[i] * vv[j];
                float d0 = mb[i*4+0] - mb[j*4+0];
                float d1 = mb[i*4+1] - mb[j*4+1];
                float d2 = mb[i*4+2] - mb[j*4+2];
                float d3 = mb[i*4+3] - mb[j*4+3];
                float psq = d0*d0 + d1*d1 + d2*d2 + d3*d3;
                float pd  = sqrtf(fmaxf(psq, 1e-12f));
                float ph  = fmaxf(DELTA_D - pd, 0.f);
                ssum += ok * ph * ph;
                np   += ok;
            }
        if (np > 0.f) { vb = ssum / np; has = 1.f; }
    }
    float pc = (tid < B*L) ? cntvG[tid] : 0.f;
    float ps = 0.f;
    for (int i = tid; i < NBLK3; i += 256) ps += pullp[i];

    float rvb = waveReduce(vb);
    float rhs = waveReduce(has);
    float rpc = waveReduce(pc);
    float rps = waveReduce(ps);
    if (lane == 0) { red[wave][0]=rvb; red[wave][1]=rhs; red[wave][2]=rpc; red[wave][3]=rps; }
    __syncthreads();
    if (tid == 0) {
        float svb = red[0][0]+red[1][0]+red[2][0]+red[3][0];
        float shs = red[0][1]+red[1][1]+red[2][1]+red[3][1];
        float spc = red[0][2]+red[1][2]+red[2][2]+red[3][2];
        float sps = red[0][3]+red[1][3]+red[2][3]+red[3][3];
        float var = (shs > 0.f) ? svb / shs : 0.f;              // push loss
        float dl  = (spc > 0.f) ? sps / fmaxf(spc, 1.f) : 0.f;  // pull loss
        out[0] = dl + var;
    }
}

// ---------------------------------------------------------------------------
extern "C" void kernel_launch(void* const* d_in, const int* in_sizes, int n_in,
                              void* d_out, int out_size, void* d_ws, size_t ws_size,
                              hipStream_t stream) {
    const int*   tgt = (const int*)d_in[0];    // targets int32 [B,H,W]
    const float* emb = (const float*)d_in[1];  // embedding fp32 [B,C,H,W]

    float* ws      = (float*)d_ws;
    float* partial = ws;                              // B*25*48 = 38400 floats
    float* meansG  = partial + (size_t)B*25*PSTRIDE;  // 640 (off 153600 B, 16B-aligned)
    float* validG  = meansG + (size_t)B*L*4;          // 160
    float* cntvG   = validG + B*L;                    // 160
    float* pullp   = cntvG + B*L;                     // 1440
    // total ws use: ~164 KB

    seg_sums_k<<<dim3(BLKX, 2, B), 256, 0, stream>>>(tgt, emb, partial);          // 2880 blocks
    pull_k<<<dim3(BLKX, B), 256, 0, stream>>>(tgt, emb, partial,
                                              meansG, validG, cntvG, pullp);      // 1440 blocks
    finish_k<<<1, 256, 0, stream>>>(pullp, meansG, validG, cntvG, (float*)d_out);
}

// Round 8
// 216.892 us; speedup vs baseline: 1.1858x; 1.1858x over previous
//
#include <hip/hip_runtime.h>
#include <math.h>

// Problem constants (match reference)
#define B 32
#define C 4
#define P (360*640)        // 230400 pixels per batch
#define L 5                // MAX_LANES
#define DELTA_V 1.0f
#define DELTA_D 6.0f

#define BLKX 45            // chunks per batch; 225 wave-steps / 45 = 5 iters exactly
#define ITER1 5
#define NBLK3 (B*BLKX)     // 1440 pull partials
#define PSTRIDE 48         // padded chunk-stride of value-major partials

__device__ __forceinline__ float waveReduce(float v) {
#pragma unroll
    for (int off = 32; off; off >>= 1) v += __shfl_down(v, off, 64);
    return v;
}

// ---------------------------------------------------------------------------
// Kernel 1: segment sums, 4-way channel split (R6 shape — proven no-spill,
// ~4.3 TB/s effective). Block = (chunk x, channel c, batch b). 2 streams,
// all 10 loads in flat register arrays (full unroll, NO rotation: R5/R7's
// rotation pipelines spilled 65-195 MB to scratch at the 64-VGPR cap).
// c==0 blocks additionally emit a packed uint8 copy of targets for kernel 2.
// Partials written VALUE-MAJOR: partial[(b*25+v)*48+x], v=c*5+l / 20+l (cnt).
// ---------------------------------------------------------------------------
__global__ __launch_bounds__(256, 4) void seg_sums_k(const int* __restrict__ tgt,
                                                     const float* __restrict__ emb,
                                                     float* __restrict__ partial,
                                                     unsigned char* __restrict__ tpk) {
    const int x = blockIdx.x, c = blockIdx.y, b = blockIdx.z;
    const int tid = threadIdx.x;

    const int4*   t4 = (const int4*)(tgt + (size_t)b * P);
    const float4* ec = (const float4*)(emb + ((size_t)b * C + c) * P);

    int4   tv[ITER1];
    float4 ev[ITER1];
#pragma unroll
    for (int it = 0; it < ITER1; ++it) {
        const int g = (x + it * BLKX) * 256 + tid;
        tv[it] = t4[g];
        ev[it] = ec[g];
    }

    // c==0: publish packed labels (uint8) for kernel 2 (7.4 MB total)
    if (c == 0) {
        uchar4* tp4 = (uchar4*)(tpk + (size_t)b * P);
#pragma unroll
        for (int it = 0; it < ITER1; ++it) {
            const int g = (x + it * BLKX) * 256 + tid;
            tp4[g] = make_uchar4((unsigned char)tv[it].x, (unsigned char)tv[it].y,
                                 (unsigned char)tv[it].z, (unsigned char)tv[it].w);
        }
    }

    float s[L], n[L];
#pragma unroll
    for (int l = 0; l < L; ++l) { s[l] = 0.f; n[l] = 0.f; }

    auto acc1 = [&](int tt, float e) {
#pragma unroll
        for (int l = 0; l < L; ++l) {
            float m = (tt == l + 1) ? 1.0f : 0.0f;
            n[l] += m;
            s[l] = fmaf(m, e, s[l]);
        }
    };
#pragma unroll
    for (int it = 0; it < ITER1; ++it) {
        acc1(tv[it].x, ev[it].x);
        acc1(tv[it].y, ev[it].y);
        acc1(tv[it].z, ev[it].z);
        acc1(tv[it].w, ev[it].w);
    }

    float vals[2*L];
#pragma unroll
    for (int l = 0; l < L; ++l) { vals[l] = s[l]; vals[L + l] = n[l]; }

    __shared__ float red[4][2*L];
    const int lane = tid & 63, wave = tid >> 6;
#pragma unroll
    for (int k = 0; k < 2*L; ++k) {
        float r = waveReduce(vals[k]);
        if (lane == 0) red[wave][k] = r;
    }
    __syncthreads();
    if (tid < L) {                      // this channel's 5 sums
        const float r = red[0][tid] + red[1][tid] + red[2][tid] + red[3][tid];
        partial[((size_t)b * 25 + c * L + tid) * PSTRIDE + x] = r;
    } else if (c == 0 && tid < 2*L) {   // counts (only once)
        const float r = red[0][tid] + red[1][tid] + red[2][tid] + red[3][tid];
        partial[((size_t)b * 25 + 20 + (tid - L)) * PSTRIDE + x] = r;
    }
}

// ---------------------------------------------------------------------------
// Kernel 2: pull loss. Prologue wave-reduces the batch's value-major partials
// into means/valid (~1 us; x==0 blocks publish for kernel 3). Main loop reads
// PACKED labels (1 B/px) + 4 fp32 planes: paired iterations, 10 loads hoisted
// per pair, flat SSA, no rotation -> fits the 64-VGPR envelope.
// ---------------------------------------------------------------------------
__global__ __launch_bounds__(256, 4) void pull_k(const unsigned char* __restrict__ tpk,
                                                 const float* __restrict__ emb,
                                                 const float* __restrict__ partial,
                                                 float* __restrict__ meansG,
                                                 float* __restrict__ validG,
                                                 float* __restrict__ cntvG,
                                                 float* __restrict__ pullp) {
    __shared__ float  praw[25];
    __shared__ float4 lmean[L + 1];   // label 0 -> zero mean
    __shared__ float  lvalid[L + 1];  // label 0 -> invalid
    __shared__ float  lred[4];
    const int xb = blockIdx.x, b = blockIdx.y;
    const int tid = threadIdx.x;
    const int lane = tid & 63, wave = tid >> 6;

    // ---- prologue: reduce partials (value-major) for batch b ----
    for (int v = wave; v < 25; v += 4) {
        float pv = (lane < BLKX) ? partial[((size_t)b * 25 + v) * PSTRIDE + lane] : 0.f;
        pv = waveReduce(pv);
        if (lane == 0) praw[v] = pv;
    }
    __syncthreads();
    if (tid < L) {
        const float cnt = praw[20 + tid];
        const bool  vld = cnt > 1.5f;          // integer count > 1
        const float inv = 1.0f / fmaxf(cnt, 1.0f);
        float4 m = make_float4(praw[tid] * inv, praw[5 + tid] * inv,
                               praw[10 + tid] * inv, praw[15 + tid] * inv);
        lmean[tid + 1]  = m;
        lvalid[tid + 1] = vld ? 1.f : 0.f;
        if (xb == 0) {                          // publish for finish_k
            *(float4*)(meansG + ((size_t)b * L + tid) * 4) = m;
            validG[b * L + tid] = vld ? 1.f : 0.f;
            cntvG[b * L + tid]  = vld ? cnt : 0.f;
        }
    }
    if (tid == 8) { lmean[0] = make_float4(0.f, 0.f, 0.f, 0.f); lvalid[0] = 0.f; }
    __syncthreads();

    // ---- main: packed labels + 4 planes, paired iterations (no rotation) ----
    const uchar4* tp4 = (const uchar4*)(tpk + (size_t)b * P);
    const float4* e0  = (const float4*)(emb + ((size_t)b * C + 0) * P);
    const float4* e1  = (const float4*)(emb + ((size_t)b * C + 1) * P);
    const float4* e2  = (const float4*)(emb + ((size_t)b * C + 2) * P);
    const float4* e3  = (const float4*)(emb + ((size_t)b * C + 3) * P);

    float acc = 0.f;
    auto proc1 = [&](int tt, float v0, float v1, float v2, float v3) {
        float4 m = lmean[tt];
        float d0 = v0 - m.x, d1 = v1 - m.y, d2 = v2 - m.z, d3 = v3 - m.w;
        float sq   = d0*d0 + d1*d1 + d2*d2 + d3*d3;
        float dist = sqrtf(fmaxf(sq, 1e-12f));
        float h    = fmaxf(dist - DELTA_V, 0.f);
        acc = fmaf(lvalid[tt] * h, h, acc);
    };
    auto consume = [&](uchar4 t, const float4& a0, const float4& a1,
                       const float4& a2, const float4& a3) {
        proc1(t.x, a0.x, a1.x, a2.x, a3.x);
        proc1(t.y, a0.y, a1.y, a2.y, a3.y);
        proc1(t.z, a0.z, a1.z, a2.z, a3.z);
        proc1(t.w, a0.w, a1.w, a2.w, a3.w);
    };

    {   // pair (0,1)
        const int g0 = xb * 256 + tid, g1 = (xb + BLKX) * 256 + tid;
        uchar4 t0 = tp4[g0], t1 = tp4[g1];
        float4 a0 = e0[g0], a1 = e1[g0], a2 = e2[g0], a3 = e3[g0];
        float4 b0 = e0[g1], b1 = e1[g1], b2 = e2[g1], b3 = e3[g1];
        consume(t0, a0, a1, a2, a3);
        consume(t1, b0, b1, b2, b3);
    }
    {   // pair (2,3)
        const int g0 = (xb + 2*BLKX) * 256 + tid, g1 = (xb + 3*BLKX) * 256 + tid;
        uchar4 t0 = tp4[g0], t1 = tp4[g1];
        float4 a0 = e0[g0], a1 = e1[g0], a2 = e2[g0], a3 = e3[g0];
        float4 b0 = e0[g1], b1 = e1[g1], b2 = e2[g1], b3 = e3[g1];
        consume(t0, a0, a1, a2, a3);
        consume(t1, b0, b1, b2, b3);
    }
    {   // iteration 4
        const int g0 = (xb + 4*BLKX) * 256 + tid;
        uchar4 t0 = tp4[g0];
        float4 a0 = e0[g0], a1 = e1[g0], a2 = e2[g0], a3 = e3[g0];
        consume(t0, a0, a1, a2, a3);
    }

    float r = waveReduce(acc);
    if (lane == 0) lred[wave] = r;
    __syncthreads();
    if (tid == 0)
        pullp[b * BLKX + xb] = lred[0] + lred[1] + lred[2] + lred[3];
}

// ---------------------------------------------------------------------------
// Kernel 3: final combine — push loss + point_count + pull partial sum
// ---------------------------------------------------------------------------
__global__ __launch_bounds__(256) void finish_k(const float* __restrict__ pullp,
                                                const float* __restrict__ meansG,
                                                const float* __restrict__ validG,
                                                const float* __restrict__ cntvG,
                                                float* __restrict__ out) {
    __shared__ float red[4][4];
    const int tid = threadIdx.x;
    const int lane = tid & 63, wave = tid >> 6;

    float vb = 0.f, has = 0.f;
    if (tid < B) {
        const float* mb = meansG + tid * L * 4;
        const float* vv = validG + tid * L;
        float ssum = 0.f, np = 0.f;
#pragma unroll
        for (int i = 0; i < L; ++i)
#pragma unroll
            for (int j = i + 1; j < L; ++j) {
                float ok = vv[i] * vv[j];
                float d0 = mb[i*4+0] - mb[j*4+0];
                float d1 = mb[i*4+1] - mb[j*4+1];
                float d2 = mb[i*4+2] - mb[j*4+2];
                float d3 = mb[i*4+3] - mb[j*4+3];
                float psq = d0*d0 + d1*d1 + d2*d2 + d3*d3;
                float pd  = sqrtf(fmaxf(psq, 1e-12f));
                float ph  = fmaxf(DELTA_D - pd, 0.f);
                ssum += ok * ph * ph;
                np   += ok;
            }
        if (np > 0.f) { vb = ssum / np; has = 1.f; }
    }
    float pc = (tid < B*L) ? cntvG[tid] : 0.f;
    float ps = 0.f;
    for (int i = tid; i < NBLK3; i += 256) ps += pullp[i];

    float rvb = waveReduce(vb);
    float rhs = waveReduce(has);
    float rpc = waveReduce(pc);
    float rps = waveReduce(ps);
    if (lane == 0) { red[wave][0]=rvb; red[wave][1]=rhs; red[wave][2]=rpc; red[wave][3]=rps; }
    __syncthreads();
    if (tid == 0) {
        float svb = red[0][0]+red[1][0]+red[2][0]+red[3][0];
        float shs = red[0][1]+red[1][1]+red[2][1]+red[3][1];
        float spc = red[0][2]+red[1][2]+red[2][2]+red[3][2];
        float sps = red[0][3]+red[1][3]+red[2][3]+red[3][3];
        float var = (shs > 0.f) ? svb / shs : 0.f;              // push loss
        float dl  = (spc > 0.f) ? sps / fmaxf(spc, 1.f) : 0.f;  // pull loss
        out[0] = dl + var;
    }
}

// ---------------------------------------------------------------------------
extern "C" void kernel_launch(void* const* d_in, const int* in_sizes, int n_in,
                              void* d_out, int out_size, void* d_ws, size_t ws_size,
                              hipStream_t stream) {
    const int*   tgt = (const int*)d_in[0];    // targets int32 [B,H,W]
    const float* emb = (const float*)d_in[1];  // embedding fp32 [B,C,H,W]

    // workspace layout: packed labels first (B*P bytes, 16B-aligned size),
    // then float scratch
    unsigned char* tpk = (unsigned char*)d_ws;                 // 7372800 B
    float* fbase   = (float*)((char*)d_ws + (size_t)B * P);    // 7372800 % 16 == 0
    float* partial = fbase;                                    // B*25*48 = 38400 floats
    float* meansG  = partial + (size_t)B * 25 * PSTRIDE;       // 640 (16B-aligned)
    float* validG  = meansG + (size_t)B * L * 4;               // 160
    float* cntvG   = validG + B * L;                           // 160
    float* pullp   = cntvG + B * L;                            // 1440
    // total ws use: ~7.5 MB

    seg_sums_k<<<dim3(BLKX, C, B), 256, 0, stream>>>(tgt, emb, partial, tpk);  // 5760 blocks
    pull_k<<<dim3(BLKX, B), 256, 0, stream>>>(tpk, emb, partial,
                                              meansG, validG, cntvG, pullp);   // 1440 blocks
    finish_k<<<1, 256, 0, stream>>>(pullp, meansG, validG, cntvG, (float*)d_out);
}